// Round 3
// baseline (32.349 us; speedup 1.0000x reference)
//
#include <hip/hip_runtime.h>

// BoundaryLoss, 2-kernel fused version.
// loss = sum sigmoid(logits[b,c,q]) * sqrt(edt2[b,q]) / (N4*C)
// edt2 = separable squared-EDT, passes in reference order B,D,H,W.
// Ring-scan early exit (f>=0 => candidates at ring r are >= r^2) is
// BIT-EXACT vs the brute-force min (min is subset-invariant when all
// skipped candidates are provably >= current best).

#define EDT_INF 1e10f

constexpr int Bb = 2, Cc = 4, Dd = 64, Hh = 96, Ww = 96;
constexpr int HW  = Hh * Ww;          // 9216
constexpr int DHW = Dd * HW;          // 589824
constexpr int N4  = Bb * DHW;         // 1179648
constexpr int WCH = 32;               // w-chunk for K1
constexpr int K1_BLOCKS = Hh * (Ww / WCH);   // 288
constexpr int K2_BLOCKS = Bb * Dd * 2;       // 256 (2 class-pairs per slice)

// ---------------- K1: init f + B-pass + D-pass ----------------
// Block tile: [B=2, D=64, WCH=32] floats (16 KB LDS) for fixed h, w-chunk.
__global__ __launch_bounds__(256) void k1_initBD(const int* __restrict__ targets,
                                                 float* __restrict__ fA,
                                                 unsigned* __restrict__ counter) {
    if (blockIdx.x == 0 && threadIdx.x == 0)
        __hip_atomic_store(counter, 0u, __ATOMIC_RELAXED, __HIP_MEMORY_SCOPE_AGENT);

    __shared__ __align__(16) float tile[Bb * Dd * WCH];
    const int h  = blockIdx.x / (Ww / WCH);
    const int wc = (blockIdx.x % (Ww / WCH)) * WCH;

    // Vectorized load: 1024 int4 -> f init
    for (int e4 = threadIdx.x; e4 < Bb * Dd * WCH / 4; e4 += 256) {
        int wq = e4 % (WCH / 4);
        int d  = (e4 / (WCH / 4)) % Dd;
        int b  = e4 / ((WCH / 4) * Dd);
        const int4 t4 = *reinterpret_cast<const int4*>(
            &targets[((b * Dd + d) * Hh + h) * Ww + wc + wq * 4]);
        float4 f4;
        f4.x = (t4.x >= 0 && t4.x < Cc) ? 0.0f : EDT_INF;
        f4.y = (t4.y >= 0 && t4.y < Cc) ? 0.0f : EDT_INF;
        f4.z = (t4.z >= 0 && t4.z < Cc) ? 0.0f : EDT_INF;
        f4.w = (t4.w >= 0 && t4.w < Cc) ? 0.0f : EDT_INF;
        *reinterpret_cast<float4*>(&tile[(b * Dd + d) * WCH + wq * 4]) = f4;
    }
    __syncthreads();

    // B-pass (N=2): d[0]=min(f0,f1+1), d[1]=min(f1,f0+1); each (d,w) owned by one thread
    for (int e = threadIdx.x; e < Dd * WCH; e += 256) {
        float f0 = tile[e], f1 = tile[Dd * WCH + e];
        tile[e]            = fminf(f0, f1 + 1.0f);
        tile[Dd * WCH + e] = fminf(f1, f0 + 1.0f);
    }
    __syncthreads();

    // D-pass ring scan, results straight to global
    for (int e = threadIdx.x; e < Bb * Dd * WCH; e += 256) {
        int w = e % WCH;
        int d = (e / WCH) % Dd;
        int b = e / (WCH * Dd);
        const float* line = &tile[b * Dd * WCH + w];   // stride WCH along d
        float best = line[d * WCH];
        for (int r = 1; r < Dd; ++r) {
            float r2 = (float)(r * r);
            if (r2 >= best) break;
            int jm = d - r, jp = d + r;
            if (jm >= 0) best = fminf(best, line[jm * WCH] + r2);
            if (jp < Dd) best = fminf(best, line[jp * WCH] + r2);
        }
        fA[((b * Dd + d) * Hh + h) * Ww + wc + w] = best;
    }
}

// ---------------- K2: H-pass + W-pass + weighted reduce + final ----------------
// Block: full [H,W] f-slice for one (b,d) in LDS (36 KB); 2 blocks per slice,
// each handling 2 of the 4 classes. Last block (atomic election) sums partials.
__global__ __launch_bounds__(512) void k2_HW_reduce(const float* __restrict__ fA,
                                                    const float* __restrict__ logits,
                                                    float* __restrict__ partials,
                                                    unsigned* __restrict__ counter,
                                                    float* __restrict__ out) {
    __shared__ __align__(16) float tile[HW];   // 36 KB
    __shared__ float sdata[512];
    __shared__ int lastFlag;

    const int slice = blockIdx.x >> 1;        // b*Dd + d
    const int cpair = blockIdx.x & 1;         // classes {0,1} or {2,3}
    const int b = slice / Dd;
    const int d = slice % Dd;

    const float* fs = fA + (size_t)slice * HW;
    for (int i4 = threadIdx.x; i4 < HW / 4; i4 += 512)
        *reinterpret_cast<float4*>(&tile[i4 * 4]) =
            *reinterpret_cast<const float4*>(&fs[i4 * 4]);
    __syncthreads();

    // H-pass (lines along h, stride Ww in LDS)
    float res[18];
    #pragma unroll
    for (int k = 0; k < 18; ++k) {
        int e = threadIdx.x + k * 512;
        int w = e % Ww, p = e / Ww;
        float best = tile[e];
        for (int r = 1; r < Hh; ++r) {
            float r2 = (float)(r * r);
            if (r2 >= best) break;
            int jm = p - r, jp = p + r;
            if (jm >= 0) best = fminf(best, tile[jm * Ww + w] + r2);
            if (jp < Hh) best = fminf(best, tile[jp * Ww + w] + r2);
        }
        res[k] = best;
    }
    __syncthreads();
    #pragma unroll
    for (int k = 0; k < 18; ++k) tile[threadIdx.x + k * 512] = res[k];
    __syncthreads();

    // W-pass (contiguous lines) -> dist = sqrt
    #pragma unroll
    for (int k = 0; k < 18; ++k) {
        int e = threadIdx.x + k * 512;
        int p = e % Ww;
        int rowbase = e - p;
        float best = tile[e];
        for (int r = 1; r < Ww; ++r) {
            float r2 = (float)(r * r);
            if (r2 >= best) break;
            int jm = p - r, jp = p + r;
            if (jm >= 0) best = fminf(best, tile[rowbase + jm] + r2);
            if (jp < Ww) best = fminf(best, tile[rowbase + jp] + r2);
        }
        res[k] = sqrtf(best);
    }
    __syncthreads();
    #pragma unroll
    for (int k = 0; k < 18; ++k) tile[threadIdx.x + k * 512] = res[k];
    __syncthreads();

    // Weighted sum: 2 classes, float4-vectorized logits
    const float* l0 = logits + ((size_t)(b * Cc + 2 * cpair) * Dd + d) * HW;
    const float* l1 = l0 + (size_t)DHW;
    float acc = 0.0f;
    for (int i4 = threadIdx.x; i4 < HW / 4; i4 += 512) {
        float4 dv = *reinterpret_cast<const float4*>(&tile[i4 * 4]);
        float4 a  = *reinterpret_cast<const float4*>(&l0[i4 * 4]);
        float4 c  = *reinterpret_cast<const float4*>(&l1[i4 * 4]);
        acc += dv.x / (1.0f + expf(-a.x)) + dv.x / (1.0f + expf(-c.x));
        acc += dv.y / (1.0f + expf(-a.y)) + dv.y / (1.0f + expf(-c.y));
        acc += dv.z / (1.0f + expf(-a.z)) + dv.z / (1.0f + expf(-c.z));
        acc += dv.w / (1.0f + expf(-a.w)) + dv.w / (1.0f + expf(-c.w));
    }

    // Block tree-reduce (fixed order, deterministic)
    sdata[threadIdx.x] = acc;
    __syncthreads();
    for (int s = 256; s > 0; s >>= 1) {
        if ((int)threadIdx.x < s) sdata[threadIdx.x] += sdata[threadIdx.x + s];
        __syncthreads();
    }

    if (threadIdx.x == 0) {
        __hip_atomic_store(&partials[blockIdx.x], sdata[0],
                           __ATOMIC_RELEASE, __HIP_MEMORY_SCOPE_AGENT);
        unsigned v = __hip_atomic_fetch_add(counter, 1u,
                           __ATOMIC_ACQ_REL, __HIP_MEMORY_SCOPE_AGENT);
        lastFlag = (v == K2_BLOCKS - 1);
    }
    __syncthreads();

    if (lastFlag) {
        float a2 = 0.0f;
        if ((int)threadIdx.x < K2_BLOCKS)
            a2 = __hip_atomic_load(&partials[threadIdx.x],
                                   __ATOMIC_ACQUIRE, __HIP_MEMORY_SCOPE_AGENT);
        sdata[threadIdx.x] = a2;
        __syncthreads();
        for (int s = 256; s > 0; s >>= 1) {
            if ((int)threadIdx.x < s) sdata[threadIdx.x] += sdata[threadIdx.x + s];
            __syncthreads();
        }
        if (threadIdx.x == 0)
            out[0] = sdata[0] * (1.0f / ((float)N4 * (float)Cc));
    }
}

extern "C" void kernel_launch(void* const* d_in, const int* in_sizes, int n_in,
                              void* d_out, int out_size, void* d_ws, size_t ws_size,
                              hipStream_t stream) {
    const float* logits  = (const float*)d_in[0];   // [B,C,D,H,W] fp32
    const int*   targets = (const int*)d_in[1];     // [B,D,H,W] int32
    float* out = (float*)d_out;

    float* fA = (float*)d_ws;                       // N4 floats
    float* partials = fA + N4;                      // K2_BLOCKS floats
    unsigned* counter = (unsigned*)(partials + K2_BLOCKS);

    k1_initBD<<<dim3(K1_BLOCKS), dim3(256), 0, stream>>>(targets, fA, counter);
    k2_HW_reduce<<<dim3(K2_BLOCKS), dim3(512), 0, stream>>>(fA, logits, partials,
                                                            counter, out);
}